// Round 13
// baseline (212.153 us; speedup 1.0000x reference)
//
#include <hip/hip_runtime.h>
#include <math.h>

#define BDIM 2
#define LLEN 1024
#define DMODEL 768
#define DINNER 1536
#define DSTATE 128
#define NH 32
#define HD 48
#define CONVD 1792
#define DPROJ 3360
#define DPROJP 3456
#define QCH 128
#define NCH 8
#define ROWS (BDIM*LLEN)

typedef unsigned short ushort_t;
typedef __attribute__((ext_vector_type(4))) short short4v;
typedef __attribute__((ext_vector_type(8))) short short8v;
typedef __attribute__((ext_vector_type(4))) float floatx4;

// ---- workspace layout (float units, no aliasing) ----
#define OFF_ZX   0ull          // zx_bf  u16 [2048][3456]
#define OFF_XBC  3538944ull    // xbc_bf u16 [2048][1792]
#define OFF_DT   5373952ull    // dt f32 [2048][32]
#define OFF_LA   5439488ull    // la2 f32 [2048][32]
#define OFF_SC   5505024ull    // Sc f32 [64][8][48][128] (read-only after stateA)
#define OFF_Y    8650752ull    // y bf16 [2048][1536]
#define OFF_PP   10223616ull   // Pp f32 [512]
#define OFF_CBT  10224640ull   // CBt bf16 [16][128][128] (131072 f)
#define OFF_BTBF 10486784ull   // BT bf16 [16][128][128]
#define OFF_XPT  10617856ull   // XpT bf16 [16][32][48][128]
#define OFF_XBF  12190720ull   // x bf16 [2048][768]
#define OFF_IPW  12977152ull   // ipw bf16 [3456][768]
#define OFF_OPW  14304256ull   // opw bf16 [768][1536]
#define OFF_YBF  14894080ull   // ybf bf16 [2048][1536]
#define OFF_GO   16466944ull   // go f32 [2048][768]

__device__ __forceinline__ ushort_t f2bf(float f) {
  union { float f; unsigned int u; } v; v.f = f;
  return (ushort_t)((v.u + 0x7FFFu + ((v.u >> 16) & 1u)) >> 16);
}
__device__ __forceinline__ float bf2f(short s) {
  union { unsigned int u; float f; } v; v.u = ((unsigned int)(ushort_t)s) << 16;
  return v.f;
}

#define GLOAD_LDS16(gptr, lptr) \
  __builtin_amdgcn_global_load_lds( \
      (const __attribute__((address_space(1))) void*)(gptr), \
      (__attribute__((address_space(3))) void*)(lptr), 16, 0, 0)

// ===== fused converts: [0,768) x ; [768,2064) ipw(+pad) ; [2064,2640) opw ====
__global__ __launch_bounds__(256) void convert_in_kernel(
    const float* __restrict__ x, const float* __restrict__ w,
    const float* __restrict__ opw, ushort_t* __restrict__ xbf,
    ushort_t* __restrict__ ipwbf, ushort_t* __restrict__ opwbf) {
  const int blk = blockIdx.x;
  if (blk < 768) {
    const int i = blk * 256 + threadIdx.x;
    const float4 a = ((const float4*)x)[i * 2];
    const float4 b = ((const float4*)x)[i * 2 + 1];
    short8v o;
    o[0] = (short)f2bf(a.x); o[1] = (short)f2bf(a.y);
    o[2] = (short)f2bf(a.z); o[3] = (short)f2bf(a.w);
    o[4] = (short)f2bf(b.x); o[5] = (short)f2bf(b.y);
    o[6] = (short)f2bf(b.z); o[7] = (short)f2bf(b.w);
    *(short8v*)(xbf + (size_t)i * 8) = o;
  } else if (blk < 2064) {
    const int i = (blk - 768) * 256 + threadIdx.x;
    const int row = i / (DMODEL / 8);
    short8v o;
    if (row < DPROJ) {
      const float4 a = ((const float4*)w)[i * 2];
      const float4 b = ((const float4*)w)[i * 2 + 1];
      o[0] = (short)f2bf(a.x); o[1] = (short)f2bf(a.y);
      o[2] = (short)f2bf(a.z); o[3] = (short)f2bf(a.w);
      o[4] = (short)f2bf(b.x); o[5] = (short)f2bf(b.y);
      o[6] = (short)f2bf(b.z); o[7] = (short)f2bf(b.w);
    } else {
      for (int j = 0; j < 8; j++) o[j] = 0;
    }
    *(short8v*)(ipwbf + (size_t)i * 8) = o;
  } else {
    const int i = (blk - 2064) * 256 + threadIdx.x;
    const float4 a = ((const float4*)opw)[i * 2];
    const float4 b = ((const float4*)opw)[i * 2 + 1];
    short8v o;
    o[0] = (short)f2bf(a.x); o[1] = (short)f2bf(a.y);
    o[2] = (short)f2bf(a.z); o[3] = (short)f2bf(a.w);
    o[4] = (short)f2bf(b.x); o[5] = (short)f2bf(b.y);
    o[6] = (short)f2bf(b.z); o[7] = (short)f2bf(b.w);
    *(short8v*)(opwbf + (size_t)i * 8) = o;
  }
}

// ============ bf16 MFMA GEMM, bf16 output (in_proj) ==========================
__global__ __launch_bounds__(256) void gemm_bf16_bfout(
    const ushort_t* __restrict__ A, const ushort_t* __restrict__ B,
    ushort_t* __restrict__ C, int M, int N, int K) {
  __shared__ __align__(16) ushort_t As[128 * 32];
  __shared__ __align__(16) ushort_t Bs[128 * 32];
  const int tid = threadIdx.x, lane = tid & 63, w = tid >> 6;
  const int wm = (w >> 1) * 64, wn = (w & 1) * 64;
  const int m0 = blockIdx.y * 128, n0 = blockIdx.x * 128;
  floatx4 acc[4][4];
#pragma unroll
  for (int i = 0; i < 4; i++)
#pragma unroll
    for (int j = 0; j < 4; j++) acc[i][j] = (floatx4){0.f, 0.f, 0.f, 0.f};
  const int srow = tid >> 2, skc = (tid & 3) * 8;
  const int kk = (lane >> 4) * 8, fr = lane & 15;
  for (int k0 = 0; k0 < K; k0 += 32) {
#pragma unroll
    for (int i = 0; i < 2; i++) {
      GLOAD_LDS16(A + (size_t)(m0 + i * 64 + srow) * K + k0 + skc,
                  As + (i * 64 + srow) * 32 + skc);
      GLOAD_LDS16(B + (size_t)(n0 + i * 64 + srow) * K + k0 + skc,
                  Bs + (i * 64 + srow) * 32 + skc);
    }
    __syncthreads();
    short8v a[4], bv[4];
#pragma unroll
    for (int mr = 0; mr < 4; mr++)
      a[mr] = *(const short8v*)(As + (wm + mr * 16 + fr) * 32 + kk);
#pragma unroll
    for (int nc = 0; nc < 4; nc++)
      bv[nc] = *(const short8v*)(Bs + (wn + nc * 16 + fr) * 32 + kk);
#pragma unroll
    for (int mr = 0; mr < 4; mr++)
#pragma unroll
      for (int nc = 0; nc < 4; nc++)
        acc[mr][nc] = __builtin_amdgcn_mfma_f32_16x16x32_bf16(
            a[mr], bv[nc], acc[mr][nc], 0, 0, 0);
    __syncthreads();
  }
  const int crow = (lane >> 4) * 4;
#pragma unroll
  for (int mr = 0; mr < 4; mr++)
#pragma unroll
    for (int nc = 0; nc < 4; nc++)
#pragma unroll
      for (int j = 0; j < 4; j++)
        C[(size_t)(m0 + wm + mr * 16 + crow + j) * N + n0 + wn + nc * 16 + fr] =
            f2bf(acc[mr][nc][j]);
}

// ============ bf16 MFMA GEMM, BN=64, fp32 out (out_proj) =====================
__global__ __launch_bounds__(256) void gemm_bf16_n64(
    const ushort_t* __restrict__ A, const ushort_t* __restrict__ B,
    float* __restrict__ C, int M, int N, int K) {
  __shared__ __align__(16) ushort_t As[128 * 32];
  __shared__ __align__(16) ushort_t Bs[64 * 32];
  const int tid = threadIdx.x, lane = tid & 63, w = tid >> 6;
  const int wm = (w >> 1) * 64, wn = (w & 1) * 32;
  const int m0 = blockIdx.y * 128, n0 = blockIdx.x * 64;
  floatx4 acc[4][2];
#pragma unroll
  for (int i = 0; i < 4; i++)
#pragma unroll
    for (int j = 0; j < 2; j++) acc[i][j] = (floatx4){0.f, 0.f, 0.f, 0.f};
  const int srow = tid >> 2, skc = (tid & 3) * 8;
  const int kk = (lane >> 4) * 8, fr = lane & 15;
  for (int k0 = 0; k0 < K; k0 += 32) {
#pragma unroll
    for (int i = 0; i < 2; i++)
      GLOAD_LDS16(A + (size_t)(m0 + i * 64 + srow) * K + k0 + skc,
                  As + (i * 64 + srow) * 32 + skc);
    GLOAD_LDS16(B + (size_t)(n0 + srow) * K + k0 + skc, Bs + srow * 32 + skc);
    __syncthreads();
    short8v a[4], bv[2];
#pragma unroll
    for (int mr = 0; mr < 4; mr++)
      a[mr] = *(const short8v*)(As + (wm + mr * 16 + fr) * 32 + kk);
#pragma unroll
    for (int nc = 0; nc < 2; nc++)
      bv[nc] = *(const short8v*)(Bs + (wn + nc * 16 + fr) * 32 + kk);
#pragma unroll
    for (int mr = 0; mr < 4; mr++)
#pragma unroll
      for (int nc = 0; nc < 2; nc++)
        acc[mr][nc] = __builtin_amdgcn_mfma_f32_16x16x32_bf16(
            a[mr], bv[nc], acc[mr][nc], 0, 0, 0);
    __syncthreads();
  }
  const int crow = (lane >> 4) * 4;
#pragma unroll
  for (int mr = 0; mr < 4; mr++)
#pragma unroll
    for (int nc = 0; nc < 2; nc++)
#pragma unroll
      for (int j = 0; j < 4; j++)
        C[(size_t)(m0 + wm + mr * 16 + crow + j) * N + n0 + wn + nc * 16 + fr] =
            acc[mr][nc][j];
}

// ======== conv1d + silu + dt, 448 threads (1 group of 4 channels each) =======
__global__ __launch_bounds__(448) void conv_dt_kernel(
    const ushort_t* __restrict__ zxb, const float* __restrict__ conv_w,
    const float* __restrict__ conv_b, const float* __restrict__ dt_bias,
    ushort_t* __restrict__ xbcb, float* __restrict__ dtbuf) {
  const int row = blockIdx.x;
  const int t = row % LLEN;
  const int tid = threadIdx.x;
  {
    const int c = tid * 4;
    const float4 cb = *(const float4*)&conv_b[c];
    float acc0 = cb.x, acc1 = cb.y, acc2 = cb.z, acc3 = cb.w;
    float4 cw[4];
#pragma unroll
    for (int j = 0; j < 4; j++) cw[j] = *(const float4*)&conv_w[(c + j) * 4];
#pragma unroll
    for (int k = 0; k < 4; k++) {
      if (t - 3 + k >= 0) {
        const short4v v = *(const short4v*)&zxb[(size_t)(row - 3 + k) * DPROJP + DINNER + c];
        acc0 += bf2f(v[0]) * ((const float*)&cw[0])[k];
        acc1 += bf2f(v[1]) * ((const float*)&cw[1])[k];
        acc2 += bf2f(v[2]) * ((const float*)&cw[2])[k];
        acc3 += bf2f(v[3]) * ((const float*)&cw[3])[k];
      }
    }
    short4v o;
    o[0] = (short)f2bf(acc0 / (1.f + expf(-acc0)));
    o[1] = (short)f2bf(acc1 / (1.f + expf(-acc1)));
    o[2] = (short)f2bf(acc2 / (1.f + expf(-acc2)));
    o[3] = (short)f2bf(acc3 / (1.f + expf(-acc3)));
    *(short4v*)&xbcb[(size_t)row * CONVD + c] = o;
  }
  if (tid < NH) {
    const float v = bf2f(zxb[(size_t)row * DPROJP + (DPROJ - NH) + tid]) + dt_bias[tid];
    dtbuf[row * NH + tid] = (v > 20.f) ? v : log1pf(expf(v));
  }
}

// ===== fused prep: [0,512) prep_x ; [512,528) prep_bt ; [528,1040) cumsum ====
__global__ __launch_bounds__(256) void prepfuse_kernel(
    const ushort_t* __restrict__ xbcb, const float* __restrict__ dtb,
    const float* __restrict__ A_log, ushort_t* __restrict__ XpT,
    ushort_t* __restrict__ BTbf, float* __restrict__ la2,
    float* __restrict__ Pp) {
  __shared__ ushort_t lb[128][136];
  __shared__ float dts[128];
  const int blk = blockIdx.x;
  const int tid = threadIdx.x;
  if (blk < 512) {
    const int c = blk & 7, h = (blk >> 3) & 31, b = blk >> 8;
    const int row0 = b * LLEN + c * QCH;
    if (tid < 128) dts[tid] = dtb[(size_t)(row0 + tid) * NH + h];
    __syncthreads();
    for (int idx = tid; idx < 128 * 12; idx += 256) {
      const int r = idx / 12, f4 = (idx % 12) * 4;
      const short4v v = *(const short4v*)&xbcb[(size_t)(row0 + r) * CONVD + h * HD + f4];
      const float d = dts[r];
      short4v o;
      o[0] = (short)f2bf(bf2f(v[0]) * d); o[1] = (short)f2bf(bf2f(v[1]) * d);
      o[2] = (short)f2bf(bf2f(v[2]) * d); o[3] = (short)f2bf(bf2f(v[3]) * d);
      *(short4v*)&lb[r][f4] = o;
    }
    __syncthreads();
    const size_t base = ((size_t)(b * NCH + c) * NH + h) * HD * 128;
    for (int idx = tid; idx < 48 * 16; idx += 256) {
      const int p = idx % 48, t0 = (idx / 48) * 8;
      short8v o;
#pragma unroll
      for (int j = 0; j < 8; j++) o[j] = lb[t0 + j][p];
      *(short8v*)&XpT[base + (size_t)p * 128 + t0] = o;
    }
  } else if (blk < 528) {
    const int bc = blk - 512;
    const int b = bc / NCH, c = bc % NCH;
    const int row0 = b * LLEN + c * QCH;
    for (int idx = tid; idx < 128 * 32; idx += 256) {
      const int t = idx >> 5, f4 = (idx & 31) * 4;
      const short4v v = *(const short4v*)&xbcb[(size_t)(row0 + t) * CONVD + DINNER + f4];
      *(short4v*)&lb[t][f4] = v;
    }
    __syncthreads();
    for (int idx = tid; idx < 128 * 16; idx += 256) {
      const int n = idx & 127, t0 = (idx >> 7) * 8;
      short8v o;
#pragma unroll
      for (int j = 0; j < 8; j++) o[j] = lb[t0 + j][n];
      *(short8v*)&BTbf[(size_t)(bc * 128 + n) * 128 + t0] = o;
    }
  } else {
    const int idx = blk - 528;
    const int c = idx & 7, h = (idx >> 3) & 31, b = idx >> 8;
    const int lane = tid & 63;
    const int row = b * LLEN + c * QCH + tid;
    float v = 0.f;
    if (tid < 128) v = dtb[(size_t)row * NH + h];
#pragma unroll
    for (int off = 1; off < 64; off <<= 1) {
      const float u = __shfl_up(v, off, 64);
      if (lane >= off) v += u;
    }
    if (tid == 63) dts[0] = v;
    __syncthreads();
    if (tid >= 64 && tid < 128) v += dts[0];
    if (tid < 128) {
      const float la2v = -expf(A_log[h]) * v * 1.44269504088896f;
      la2[(size_t)row * NH + h] = la2v;
      if (tid == 127) Pp[(b * NH + h) * NCH + c] = exp2f(la2v);
    }
  }
}

// ===== fused: [0,512) stateA per (b,c,h) ; [512,528) cbt per (b,c) ===========
__global__ __launch_bounds__(256) void stateA_cbt_kernel(
    const ushort_t* __restrict__ XpT, const ushort_t* __restrict__ BTbf,
    const ushort_t* __restrict__ xbcb, const float* __restrict__ la2,
    float* __restrict__ Sc, ushort_t* __restrict__ CBtb) {
  __shared__ float ew[128];
  const int blk = blockIdx.x;
  const int tid = threadIdx.x, lane = tid & 63, w = tid >> 6;
  const int fr = lane & 15, kk = (lane >> 4) * 8;
  if (blk < 512) {
    const int c = blk & 7, h = (blk >> 3) & 31, b = blk >> 8;
    const int bc = b * NCH + c, bh = b * NH + h;
    const int row0 = b * LLEN + c * QCH;
    const float laL = la2[(size_t)(row0 + 127) * NH + h];
    if (tid < 128) ew[tid] = exp2f(laL - la2[(size_t)(row0 + tid) * NH + h]);
    __syncthreads();
    const int wn = w * 32;
    const size_t xbase = ((size_t)bc * NH + h) * HD * 128;
    floatx4 acc[3][2];
#pragma unroll
    for (int i = 0; i < 3; i++)
#pragma unroll
      for (int j = 0; j < 2; j++) acc[i][j] = (floatx4){0.f, 0.f, 0.f, 0.f};
    for (int ki = 0; ki < 4; ki++) {
      const int kg = ki * 32 + kk;
      short8v a[3], bv[2];
#pragma unroll
      for (int mt = 0; mt < 3; mt++) {
        const short8v raw = *(const short8v*)&XpT[xbase + (size_t)(mt * 16 + fr) * 128 + kg];
        short8v s;
#pragma unroll
        for (int e = 0; e < 8; e++) s[e] = (short)f2bf(bf2f(raw[e]) * ew[kg + e]);
        a[mt] = s;
      }
#pragma unroll
      for (int nt = 0; nt < 2; nt++)
        bv[nt] = *(const short8v*)&BTbf[(size_t)(bc * 128 + wn + nt * 16 + fr) * 128 + kg];
#pragma unroll
      for (int mt = 0; mt < 3; mt++)
#pragma unroll
        for (int nt = 0; nt < 2; nt++)
          acc[mt][nt] = __builtin_amdgcn_mfma_f32_16x16x32_bf16(
              a[mt], bv[nt], acc[mt][nt], 0, 0, 0);
    }
    const int crow = (lane >> 4) * 4;
    float* sc = Sc + (size_t)(bh * NCH + c) * (HD * DSTATE);
#pragma unroll
    for (int mt = 0; mt < 3; mt++)
#pragma unroll
      for (int nt = 0; nt < 2; nt++)
#pragma unroll
        for (int j = 0; j < 4; j++)
          sc[(size_t)(mt * 16 + crow + j) * 128 + wn + nt * 16 + fr] = acc[mt][nt][j];
  } else {
    const int bc = blk - 512;
    const int b = bc / NCH, c = bc % NCH;
    const int row0 = b * LLEN + c * QCH;
    const int wm = w * 32;
    floatx4 acc[2][8];
#pragma unroll
    for (int i = 0; i < 2; i++)
#pragma unroll
      for (int j = 0; j < 8; j++) acc[i][j] = (floatx4){0.f, 0.f, 0.f, 0.f};
    for (int ki = 0; ki < 4; ki++) {
      const int kg = ki * 32 + kk;
      short8v a[2], bv[8];
#pragma unroll
      for (int mt = 0; mt < 2; mt++)
        a[mt] = *(const short8v*)&xbcb[(size_t)(row0 + wm + mt * 16 + fr) * CONVD +
                                       DINNER + DSTATE + kg];
#pragma unroll
      for (int nt = 0; nt < 8; nt++)
        bv[nt] = *(const short8v*)&xbcb[(size_t)(row0 + nt * 16 + fr) * CONVD +
                                        DINNER + kg];
#pragma unroll
      for (int mt = 0; mt < 2; mt++)
#pragma unroll
        for (int nt = 0; nt < 8; nt++)
          acc[mt][nt] = __builtin_amdgcn_mfma_f32_16x16x32_bf16(
              a[mt], bv[nt], acc[mt][nt], 0, 0, 0);
    }
    const int crow = (lane >> 4) * 4;
#pragma unroll
    for (int mt = 0; mt < 2; mt++)
#pragma unroll
      for (int nt = 0; nt < 8; nt++)
#pragma unroll
        for (int j = 0; j < 4; j++)
          CBtb[(size_t)(bc * 128 + wm + mt * 16 + crow + j) * 128 + nt * 16 + fr] =
              f2bf(acc[mt][nt][j]);
  }
}

// ======== Pass C (+inlined combine): Y -> bf16 ===============================
__global__ __launch_bounds__(256) void ykernel(
    const ushort_t* __restrict__ CBtb, const ushort_t* __restrict__ XpT,
    const ushort_t* __restrict__ xbcb, const float* __restrict__ Sc,
    const float* __restrict__ Pp, const float* __restrict__ la2,
    ushort_t* __restrict__ yb) {
  const int c = blockIdx.x, h = blockIdx.y, b = blockIdx.z;
  const int bc = b * NCH + c, bh = b * NH + h;
  const int row0 = b * LLEN + c * QCH;
  const int tid = threadIdx.x, lane = tid & 63, w = tid >> 6;
  __shared__ float laL[128], el[128];
  __shared__ float hls[48][132];   // +4 pad: row stride 528B -> 2-way bank alias (free)
  if (tid < 128) {
    const float v = la2[(size_t)(row0 + tid) * NH + h];
    laL[tid] = v; el[tid] = exp2f(v);
  }
  // ---- inlined chunk-combine: h_in(c) = sum_{s<c} (prod_{s<d<c} Pp[d]) S(s)
  {
    float hacc[24];
#pragma unroll
    for (int i = 0; i < 24; i++) hacc[i] = 0.f;
    float factor = 1.f;
    const float* scb = Sc + (size_t)bh * NCH * (HD * DSTATE);
    for (int s = c - 1; s >= 0; --s) {
      const float* sp = scb + (size_t)s * (HD * DSTATE);
      const float pf = factor;
#pragma unroll
      for (int i = 0; i < 6; i++) {
        const int e = (tid + i * 256) * 4;
        const float4 v = *(const float4*)&sp[e];
        hacc[i * 4 + 0] += pf * v.x; hacc[i * 4 + 1] += pf * v.y;
        hacc[i * 4 + 2] += pf * v.z; hacc[i * 4 + 3] += pf * v.w;
      }
      factor *= Pp[bh * NCH + s];
    }
#pragma unroll
    for (int i = 0; i < 6; i++) {
      const int e = (tid + i * 256) * 4;
      const int p = e >> 7, n = e & 127;
      *(float4*)&hls[p][n] =
          make_float4(hacc[i * 4], hacc[i * 4 + 1], hacc[i * 4 + 2], hacc[i * 4 + 3]);
    }
  }
  __syncthreads();
  const int wm = w * 32;
  const int fr = lane & 15, kk = (lane >> 4) * 8;
  const size_t xbase = ((size_t)bc * NH + h) * HD * 128;
  floatx4 acc[2][3];
#pragma unroll
  for (int i = 0; i < 2; i++)
#pragma unroll
    for (int j = 0; j < 3; j++) acc[i][j] = (floatx4){0.f, 0.f, 0.f, 0.f};

  // part 1: intra-chunk masked (CBt .* mask) @ X'
  for (int ki = 0; ki < 4; ki++) {
    const int kg = ki * 32 + kk;
    short8v a[2], bv[3];
#pragma unroll
    for (int mt = 0; mt < 2; mt++) {
      const int t = wm + mt * 16 + fr;
      const float lt = laL[t];
      const short8v cb = *(const short8v*)&CBtb[(size_t)(bc * 128 + t) * 128 + kg];
      short8v s;
#pragma unroll
      for (int e = 0; e < 8; e++) {
        const int sidx = kg + e;
        const float m = (t >= sidx) ? exp2f(lt - laL[sidx]) : 0.f;
        s[e] = (short)f2bf(bf2f(cb[e]) * m);
      }
      a[mt] = s;
    }
#pragma unroll
    for (int nt = 0; nt < 3; nt++)
      bv[nt] = *(const short8v*)&XpT[xbase + (size_t)(nt * 16 + fr) * 128 + kg];
#pragma unroll
    for (int mt = 0; mt < 2; mt++)
#pragma unroll
      for (int nt = 0; nt < 3; nt++)
        acc[mt][nt] = __builtin_amdgcn_mfma_f32_16x16x32_bf16(
            a[mt], bv[nt], acc[mt][nt], 0, 0, 0);
  }
  // part 2: inter-chunk (C .* el) @ h_in (from LDS)
  for (int ki = 0; ki < 4; ki++) {
    const int kg = ki * 32 + kk;
    short8v a[2], bv[3];
#pragma unroll
    for (int mt = 0; mt < 2; mt++) {
      const int t = wm + mt * 16 + fr;
      const float scl = el[t];
      const short8v raw = *(const short8v*)&xbcb[(size_t)(row0 + t) * CONVD +
                                                 DINNER + DSTATE + kg];
      short8v s;
#pragma unroll
      for (int e = 0; e < 8; e++) s[e] = (short)f2bf(bf2f(raw[e]) * scl);
      a[mt] = s;
    }
#pragma unroll
    for (int nt = 0; nt < 3; nt++) {
      const float* hp = &hls[nt * 16 + fr][kg];
      const float4 u0 = *(const float4*)hp;
      const float4 u1 = *(const float4*)(hp + 4);
      const float f[8] = {u0.x, u0.y, u0.z, u0.w, u1.x, u1.y, u1.z, u1.w};
      short8v s;
#pragma unroll
      for (int e = 0; e < 8; e++) s[e] = (short)f2bf(f[e]);
      bv[nt] = s;
    }
#pragma unroll
    for (int mt = 0; mt < 2; mt++)
#pragma unroll
      for (int nt = 0; nt < 3; nt++)
        acc[mt][nt] = __builtin_amdgcn_mfma_f32_16x16x32_bf16(
            a[mt], bv[nt], acc[mt][nt], 0, 0, 0);
  }
  const int crow = (lane >> 4) * 4;
#pragma unroll
  for (int mt = 0; mt < 2; mt++)
#pragma unroll
    for (int nt = 0; nt < 3; nt++)
#pragma unroll
      for (int j = 0; j < 4; j++) {
        const int row = row0 + wm + mt * 16 + crow + j;
        yb[(size_t)row * DINNER + h * HD + nt * 16 + fr] = f2bf(acc[mt][nt][j]);
      }
}

// ===== gate (silu(z)) + RMSNorm over 1536, 192 threads =======================
__global__ __launch_bounds__(192) void gate_rms_kernel(
    const ushort_t* __restrict__ zxb, const ushort_t* __restrict__ xbcb,
    const float* __restrict__ Dv, const float* __restrict__ rms_w,
    const ushort_t* __restrict__ yb, ushort_t* __restrict__ ybf) {
  const int row = blockIdx.x;
  const int tid = threadIdx.x;
  __shared__ float sred[3];
  float g[8];
  float ss = 0.f;
  const int e0 = tid * 8;
  {
    const short8v xv = *(const short8v*)&xbcb[(size_t)row * CONVD + e0];
    const short8v zv = *(const short8v*)&zxb[(size_t)row * DPROJP + e0];
    const short8v yv = *(const short8v*)&yb[(size_t)row * DINNER + e0];
#pragma unroll
    for (int j = 0; j < 8; j++) {
      const int e = e0 + j;
      const float yf = bf2f(yv[j]) + Dv[e / HD] * bf2f(xv[j]);
      const float z = bf2f(zv[j]);
      const float gv = yf * (z / (1.f + expf(-z)));
      g[j] = gv;
      ss += gv * gv;
    }
  }
#pragma unroll
  for (int off = 32; off; off >>= 1) ss += __shfl_down(ss, off, 64);
  if ((tid & 63) == 0) sred[tid >> 6] = ss;
  __syncthreads();
  const float tot = sred[0] + sred[1] + sred[2];
  const float scale = rsqrtf(tot / DINNER + 1e-5f);
  {
    const float4 w0 = *(const float4*)&rms_w[e0];
    const float4 w1 = *(const float4*)&rms_w[e0 + 4];
    const float wf[8] = {w0.x, w0.y, w0.z, w0.w, w1.x, w1.y, w1.z, w1.w};
    short8v o;
#pragma unroll
    for (int j = 0; j < 8; j++) o[j] = (short)f2bf(g[j] * scale * wf[j]);
    *(short8v*)&ybf[(size_t)row * DINNER + e0] = o;
  }
}

// ================= residual + LayerNorm over 768 =============================
__global__ __launch_bounds__(256) void resid_ln_kernel(
    const float* __restrict__ go, const float* __restrict__ x,
    const float* __restrict__ ln_w, const float* __restrict__ ln_b,
    float* __restrict__ out) {
  const int row = blockIdx.x;
  const int tid = threadIdx.x;
  __shared__ float sred[4];
  __shared__ float sred2[4];
  float r[3];
  float s = 0.f;
#pragma unroll
  for (int i = 0; i < 3; i++) {
    const int e = tid + i * 256;
    r[i] = go[(size_t)row * DMODEL + e] + x[(size_t)row * DMODEL + e];
    s += r[i];
  }
#pragma unroll
  for (int off = 32; off; off >>= 1) s += __shfl_down(s, off, 64);
  if ((tid & 63) == 0) sred[tid >> 6] = s;
  __syncthreads();
  const float mu = (sred[0] + sred[1] + sred[2] + sred[3]) * (1.f / DMODEL);
  float s2 = 0.f;
#pragma unroll
  for (int i = 0; i < 3; i++) {
    const float d = r[i] - mu;
    s2 += d * d;
  }
#pragma unroll
  for (int off = 32; off; off >>= 1) s2 += __shfl_down(s2, off, 64);
  if ((tid & 63) == 0) sred2[tid >> 6] = s2;
  __syncthreads();
  const float var = (sred2[0] + sred2[1] + sred2[2] + sred2[3]) * (1.f / DMODEL);
  const float inv = rsqrtf(var + 1e-5f);
#pragma unroll
  for (int i = 0; i < 3; i++) {
    const int e = tid + i * 256;
    out[(size_t)row * DMODEL + e] = (r[i] - mu) * inv * ln_w[e] + ln_b[e];
  }
}

// ================= launch ====================================================
extern "C" void kernel_launch(void* const* d_in, const int* in_sizes, int n_in,
                              void* d_out, int out_size, void* d_ws, size_t ws_size,
                              hipStream_t stream) {
  const float* x          = (const float*)d_in[0];
  const float* in_proj_w  = (const float*)d_in[1];
  const float* conv_w     = (const float*)d_in[2];
  const float* conv_b     = (const float*)d_in[3];
  const float* dt_bias    = (const float*)d_in[4];
  const float* A_log      = (const float*)d_in[5];
  const float* Dv         = (const float*)d_in[6];
  const float* rms_w      = (const float*)d_in[7];
  const float* out_proj_w = (const float*)d_in[8];
  const float* ln_w       = (const float*)d_in[9];
  const float* ln_b       = (const float*)d_in[10];
  float* out = (float*)d_out;
  float* ws  = (float*)d_ws;

  ushort_t* zxb   = (ushort_t*)(ws + OFF_ZX);
  ushort_t* xbcb  = (ushort_t*)(ws + OFF_XBC);
  float* dtb  = ws + OFF_DT;
  float* la2  = ws + OFF_LA;
  float* Sc   = ws + OFF_SC;
  ushort_t* ybuf = (ushort_t*)(ws + OFF_Y);
  float* Pp   = ws + OFF_PP;
  ushort_t* CBtb  = (ushort_t*)(ws + OFF_CBT);
  ushort_t* BTbf  = (ushort_t*)(ws + OFF_BTBF);
  ushort_t* XpT   = (ushort_t*)(ws + OFF_XPT);
  ushort_t* xbf   = (ushort_t*)(ws + OFF_XBF);
  ushort_t* ipwbf = (ushort_t*)(ws + OFF_IPW);
  ushort_t* opwbf = (ushort_t*)(ws + OFF_OPW);
  ushort_t* ybf   = (ushort_t*)(ws + OFF_YBF);
  float*    go    = ws + OFF_GO;

  // 1) input converts
  convert_in_kernel<<<2640, 256, 0, stream>>>(x, in_proj_w, out_proj_w,
                                              xbf, ipwbf, opwbf);
  // 2) in_proj -> bf16 zx
  gemm_bf16_bfout<<<dim3(DPROJP / 128, ROWS / 128), 256, 0, stream>>>(
      xbf, ipwbf, zxb, ROWS, DPROJP, DMODEL);
  // 3) conv + silu + dt
  conv_dt_kernel<<<ROWS, 448, 0, stream>>>(zxb, conv_w, conv_b, dt_bias, xbcb, dtb);
  // 4) fused preps
  prepfuse_kernel<<<1040, 256, 0, stream>>>(xbcb, dtb, A_log, XpT, BTbf, la2, Pp);
  // 5) fused stateA | cbt
  stateA_cbt_kernel<<<528, 256, 0, stream>>>(XpT, BTbf, xbcb, la2, Sc, CBtb);
  // 6) y emission (+inlined chunk combine) -> bf16
  ykernel<<<dim3(NCH, NH, BDIM), 256, 0, stream>>>(CBtb, XpT, xbcb, Sc, Pp, la2, ybuf);
  // 7) gate + RMSNorm -> bf16
  gate_rms_kernel<<<ROWS, 192, 0, stream>>>(zxb, xbcb, Dv, rms_w, ybuf, ybf);
  // 8) out_proj
  gemm_bf16_n64<<<dim3(DMODEL / 64, ROWS / 128), 256, 0, stream>>>(
      ybf, opwbf, go, ROWS, DMODEL, DINNER);
  // 9) residual + LayerNorm
  resid_ln_kernel<<<ROWS, 256, 0, stream>>>(go, x, ln_w, ln_b, out);
}